// Round 10
// baseline (127.131 us; speedup 1.0000x reference)
//
#include <hip/hip_runtime.h>
#include <hip/hip_bf16.h>
#include <math.h>

#define EPSV 1e-5f
#define HD   128
#define AROW 40   // SA bf16 row stride: 80B = 5 quartets, gcd(5,8)=1 -> balanced
#define WROW 24   // Wt bf16 row stride: 48B = 3 quartets, gcd(3,8)=1 -> balanced

typedef __attribute__((ext_vector_type(8))) short bf16x8;   // 8 bf16 = 4 VGPRs
typedef __attribute__((ext_vector_type(4))) float f32x4;

// TWO (b,t) halos per block, processed sequentially through one SA buffer;
// tail GEMVs run once for both rows with identical W address streams across
// the row pairs (L1 reuse -> W1/W2 L2 traffic halved vs R9). blockDim=256.
// Numerics (verified R5-R9): 10 per-(b,t)-constant features exact fp32
// (cvec, folded into MFMA acc init); 9 varying features compensated bf16
// MFMA (A: hi k0..8 | lo k16..24; B1=whi, B2=wlo => exact (ahi+alo)*w).
__global__ __launch_bounds__(256, 4) void net_fused(
    const float* __restrict__ x0g, const float* __restrict__ xg,
    const int*   __restrict__ Ng,  const float* __restrict__ basisg,
    const float* __restrict__ vg,  const float* __restrict__ Pg,
    const float* __restrict__ W0,  const float* __restrict__ b0,
    const float* __restrict__ W1,  const float* __restrict__ b1,
    const float* __restrict__ W2,  const float* __restrict__ b2,
    float* __restrict__ out, int Tn, int NDn, int BT)
{
    __shared__ __align__(16) __hip_bfloat16 SA[256 * AROW];   // reused per halo
    __shared__ __align__(16) __hip_bfloat16 Wt1[128 * WROW];  // whi (16 used/row)
    __shared__ __align__(16) __hip_bfloat16 Wt2[128 * WROW];  // wlo
    __shared__ float cvec[HD];         // per-halo constant-feature contribution
    __shared__ float hvec2[2][HD];     // pooled results for both halos
    __shared__ float h1vec2[2][HD];    // layer-1 activations
    __shared__ float vred2[2][4][3];   // per-halo v-mean wave partials

    const int bt0  = blockIdx.x * 2;
    const int tid  = threadIdx.x;
    const int lane = tid & 63;
    const int wave = tid >> 6;
    const int quad = lane >> 4;
    const int lm   = lane & 15;
    const float inv_nd = 1.0f / (float)NDn;

    // ---- Wt staging by threads 0..127 (once; visible after first barrier) ----
    if (tid < 128) {
        const int RV[9] = {0, 1, 2, 3, 14, 15, 16, 17, 18};
        __hip_bfloat16 r1[16], r2[16];
        #pragma unroll
        for (int kk = 0; kk < 16; ++kk) {
            r1[kk] = __float2bfloat16(0.0f);
            r2[kk] = __float2bfloat16(0.0f);
        }
        if (tid < 127) {
            #pragma unroll
            for (int kk = 0; kk < 9; ++kk) {
                const float wv = W0[RV[kk] * 127 + tid];   // coalesced across tid
                const __hip_bfloat16 hi = __float2bfloat16(wv);
                r1[kk] = hi;
                r2[kk] = __float2bfloat16(wv - __bfloat162float(hi));
            }
        }
        bf16x8* d1 = reinterpret_cast<bf16x8*>(&Wt1[tid * WROW]);
        bf16x8* d2 = reinterpret_cast<bf16x8*>(&Wt2[tid * WROW]);
        const bf16x8* s1v = reinterpret_cast<const bf16x8*>(r1);
        const bf16x8* s2v = reinterpret_cast<const bf16x8*>(r2);
        d1[0] = s1v[0]; d1[1] = s1v[1];
        d2[0] = s2v[0]; d2[1] = s2v[1];
    }

    for (int h = 0; h < 2; ++h) {
        const int bt = bt0 + h;
        const int b  = bt / Tn;

        // ---- per-particle loads for this halo ----
        const long pbase = ((long)bt * NDn + tid) * 3;
        const float xi0 = xg[pbase+0], xi1 = xg[pbase+1], xi2 = xg[pbase+2];
        const float vi0 = vg[pbase+0], vi1 = vg[pbase+1], vi2 = vg[pbase+2];

        // ---- v0 mean: wave shuffle reduce -> vred2[h] (own buffer: no WAR
        //      hazard with the previous halo's readers) ----
        float s0 = vi0, s1 = vi1, s2 = vi2;
        #pragma unroll
        for (int off = 32; off > 0; off >>= 1) {
            s0 += __shfl_down(s0, off);
            s1 += __shfl_down(s1, off);
            s2 += __shfl_down(s2, off);
        }
        if (lane == 0) {
            vred2[h][wave][0] = s0; vred2[h][wave][1] = s1; vred2[h][wave][2] = s2;
        }
        // Barrier B: publishes vred2[h] AND (for h=1) guarantees halo-0 MFMA
        // finished reading SA/cvec before we overwrite them.
        __syncthreads();

        const float v00 = (vred2[h][0][0]+vred2[h][1][0]+vred2[h][2][0]+vred2[h][3][0]) * inv_nd;
        const float v01 = (vred2[h][0][1]+vred2[h][1][1]+vred2[h][2][1]+vred2[h][3][1]) * inv_nd;
        const float v02 = (vred2[h][0][2]+vred2[h][1][2]+vred2[h][2][2]+vred2[h][3][2]) * inv_nd;

        // ---- per-(b,t) scalars ----
        const float p0 = x0g[bt*3+0], p1 = x0g[bt*3+1], p2 = x0g[bt*3+2];
        float bas[3][3];
        #pragma unroll
        for (int k = 0; k < 3; ++k)
            #pragma unroll
            for (int c = 0; c < 3; ++c)
                bas[k][c] = basisg[(b*3 + k)*3 + c];

        const float x0n  = sqrtf(p0*p0 + p1*p1 + p2*p2) + EPSV;
        const float ix0n = 1.0f / x0n;
        const float x0u0 = p0*ix0n, x0u1 = p1*ix0n, x0u2 = p2*ix0n;

        const float v0n  = sqrtf(v00*v00 + v01*v01 + v02*v02) + EPSV;
        const float iv0n = 1.0f / v0n;
        const float v0u0 = v00*iv0n, v0u1 = v01*iv0n, v0u2 = v02*iv0n;

        const float logN = log1pf((float)Ng[bt]);

        // ---- exact fp32 constant-feature contribution + hvec init ----
        if (tid < 128) {
            float c = 0.0f;
            if (tid < 127) {
                float fc[10];
                fc[0] = logN;
                fc[1] = x0n;
                fc[2] = x0u0*bas[0][0] + x0u1*bas[0][1] + x0u2*bas[0][2];
                fc[3] = x0u0*bas[1][0] + x0u1*bas[1][1] + x0u2*bas[1][2];
                fc[4] = x0u0*bas[2][0] + x0u1*bas[2][1] + x0u2*bas[2][2];
                fc[5] = v0n;
                fc[6] = v0u0*bas[0][0] + v0u1*bas[0][1] + v0u2*bas[0][2];
                fc[7] = v0u0*bas[1][0] + v0u1*bas[1][1] + v0u2*bas[1][2];
                fc[8] = v0u0*bas[2][0] + v0u1*bas[2][1] + v0u2*bas[2][2];
                fc[9] = x0u0*v0u0 + x0u1*v0u1 + x0u2*v0u2;
                c = b0[tid];
                #pragma unroll
                for (int i = 0; i < 10; ++i)
                    c = fmaf(fc[i], W0[(4 + i) * 127 + tid], c);
            }
            cvec[tid] = c;
            hvec2[h][tid] = (tid == 127) ? logN : 0.0f;   // atomic base
        }

        // ---- varying features -> SA row via 4x ds_write_b128 ----
        {
            const float xn  = sqrtf(xi0*xi0 + xi1*xi1 + xi2*xi2) + EPSV;
            const float ixn = 1.0f / xn;
            const float xu0 = xi0*ixn, xu1 = xi1*ixn, xu2 = xi2*ixn;

            const float c0 = vi0 - v00, c1 = vi1 - v01, c2 = vi2 - v02;
            const float vn  = sqrtf(c0*c0 + c1*c1 + c2*c2) + EPSV;
            const float ivn = 1.0f / vn;
            const float vu0 = c0*ivn, vu1 = c1*ivn, vu2 = c2*ivn;

            float f[9];
            f[0] = xn;                                            // W0 row 0
            f[1] = xu0*bas[0][0] + xu1*bas[0][1] + xu2*bas[0][2]; // row 1
            f[2] = xu0*bas[1][0] + xu1*bas[1][1] + xu2*bas[1][2]; // row 2
            f[3] = xu0*bas[2][0] + xu1*bas[2][1] + xu2*bas[2][2]; // row 3
            f[4] = vn;                                            // row 14
            f[5] = vu0*bas[0][0] + vu1*bas[0][1] + vu2*bas[0][2]; // row 15
            f[6] = vu0*bas[1][0] + vu1*bas[1][1] + vu2*bas[1][2]; // row 16
            f[7] = vu0*bas[2][0] + vu1*bas[2][1] + vu2*bas[2][2]; // row 17
            f[8] = xu0*vu0 + xu1*vu1 + xu2*vu2;                   // row 18

            __hip_bfloat16 row[32];
            #pragma unroll
            for (int kk = 0; kk < 32; ++kk) row[kk] = __float2bfloat16(0.0f);
            #pragma unroll
            for (int kk = 0; kk < 9; ++kk) {
                const __hip_bfloat16 hi = __float2bfloat16(f[kk]);
                row[kk]      = hi;
                row[16 + kk] = __float2bfloat16(f[kk] - __bfloat162float(hi));
            }
            bf16x8* dst = reinterpret_cast<bf16x8*>(&SA[tid * AROW]);
            const bf16x8* src = reinterpret_cast<const bf16x8*>(row);
            dst[0] = src[0]; dst[1] = src[1]; dst[2] = src[2]; dst[3] = src[3];
        }
        __syncthreads();   // Barrier C: SA + cvec + hvec init ready

        // ---- layer 0 MFMA: wave w owns particles [w*64, w*64+64) ----
        {
            const int koff = (quad & 1) * 8;   // quads 2/3 re-read same Wt data

            bf16x8 bf1[8], bf2[8];
            f32x4  cin[8];
            #pragma unroll
            for (int nt = 0; nt < 8; ++nt) {
                bf1[nt] = *reinterpret_cast<const bf16x8*>(&Wt1[(nt*16 + lm) * WROW + koff]);
                bf2[nt] = *reinterpret_cast<const bf16x8*>(&Wt2[(nt*16 + lm) * WROW + koff]);
                const float cl = cvec[nt*16 + lm];
                cin[nt] = (f32x4){cl, cl, cl, cl};
            }

            float pooled[8];
            #pragma unroll
            for (int nt = 0; nt < 8; ++nt) pooled[nt] = 0.0f;

            #pragma unroll
            for (int mt = 0; mt < 4; ++mt) {
                const bf16x8 af = *reinterpret_cast<const bf16x8*>(
                    &SA[(wave*64 + mt*16 + lm) * AROW + quad*8]);
                #pragma unroll
                for (int nt = 0; nt < 8; ++nt) {
                    f32x4 acc = __builtin_amdgcn_mfma_f32_16x16x32_bf16(af, bf1[nt], cin[nt], 0, 0, 0);
                    acc = __builtin_amdgcn_mfma_f32_16x16x32_bf16(af, bf2[nt], acc, 0, 0, 0);
                    #pragma unroll
                    for (int r = 0; r < 4; ++r)
                        pooled[nt] += fmaxf(acc[r], 0.01f*acc[r]);   // leaky_relu
                }
            }
            #pragma unroll
            for (int nt = 0; nt < 8; ++nt) {
                pooled[nt] += __shfl_xor(pooled[nt], 16);
                pooled[nt] += __shfl_xor(pooled[nt], 32);
            }
            if (lane < 16) {
                #pragma unroll
                for (int nt = 0; nt < 8; ++nt) {
                    const int n = nt*16 + lane;
                    if (n < 127) atomicAdd(&hvec2[h][n], pooled[nt] * inv_nd);
                }
            }
        }
    }
    __syncthreads();   // Barrier D: both halos pooled

    // ---- tail: thread (r = tid>>7, j = tid&127); rows share W addr stream ----
    const int r  = tid >> 7;
    const int j  = tid & 127;
    {
        float a = b1[j];
        #pragma unroll 16
        for (int k = 0; k < HD; ++k)
            a = fmaf(hvec2[r][k], W1[k*HD + j], a);
        h1vec2[r][j] = fmaxf(a, 0.01f*a);
    }
    __syncthreads();   // Barrier E

    {
        const int bt = bt0 + r;
        float a = b2[j];
        #pragma unroll 16
        for (int k = 0; k < HD; ++k)
            a = fmaf(h1vec2[r][k], W2[k*HD + j], a);
        out[(long)bt * HD + j] = a / Pg[bt / Tn];
    }
}

extern "C" void kernel_launch(void* const* d_in, const int* in_sizes, int n_in,
                              void* d_out, int out_size, void* d_ws, size_t ws_size,
                              hipStream_t stream) {
    const float* x0    = (const float*)d_in[0];
    const float* x     = (const float*)d_in[1];
    const int*   N     = (const int*)  d_in[2];
    const float* basis = (const float*)d_in[3];
    const float* v     = (const float*)d_in[4];
    const float* P200c = (const float*)d_in[5];
    const float* W0    = (const float*)d_in[6];
    const float* b0    = (const float*)d_in[7];
    const float* W1    = (const float*)d_in[8];
    const float* b1    = (const float*)d_in[9];
    const float* W2    = (const float*)d_in[10];
    const float* b2    = (const float*)d_in[11];
    float* out = (float*)d_out;

    const int B  = in_sizes[5];                 // P200c is [B]
    const int T  = in_sizes[2] / B;             // N is [B,T]
    const int ND = in_sizes[1] / (in_sizes[2] * 3);  // x is [B,T,ND,3]
    const int BT = B * T;

    hipLaunchKernelGGL(net_fused, dim3(BT / 2), dim3(256), 0, stream,
                       x0, x, N, basis, v, P200c, W0, b0, W1, b1, W2, b2,
                       out, T, ND, BT);
}